// Round 1
// baseline (89.582 us; speedup 1.0000x reference)
//
#include <hip/hip_runtime.h>

typedef __bf16 bf16x8 __attribute__((ext_vector_type(8)));
typedef float  f32x4  __attribute__((ext_vector_type(4)));

__device__ __forceinline__ unsigned short f2bf(float f) {
  unsigned u = __float_as_uint(f);
  u += 0x7FFFu + ((u >> 16) & 1u);   // round-to-nearest-even
  return (unsigned short)(u >> 16);
}

#define WF_BYTES 147456  // 9 taps * 2 ci-chunks * 8 cout-blocks * 64 lanes * 16 B

// ---- weight transform: W[128][64][3][3] f32 -> bf16 MFMA B-fragment layout
// wf[(((kh*3+kw)*2+ck)*8+nb)*64 + lane][j] = W[nb*16+(lane&15)][ck*32+(lane>>4)*8+j][kh][kw]
__global__ __launch_bounds__(64) void wxf_746(const float* __restrict__ w,
                                              unsigned short* __restrict__ wf) {
  const int b = blockIdx.x;            // 0..143
  const int lane = threadIdx.x;        // 0..63
  const int nb = b & 7, ck = (b >> 3) & 1, pos = b >> 4;
  const int kh = pos / 3, kw = pos % 3;
  const int co = nb * 16 + (lane & 15);
  const int ci0 = ck * 32 + ((lane >> 4) << 3);
  unsigned short* o = wf + ((size_t)(b * 64 + lane) << 3);
#pragma unroll
  for (int j = 0; j < 8; ++j)
    o[j] = f2bf(w[((co * 64 + ci0 + j) * 3 + kh) * 3 + kw]);
}

// ---- fused conv3x3 + bias + relu + maxpool2x2, implicit GEMM, bf16 MFMA
// 1 WG = (n, pooled row hpair). Tile: conv rows h0,h0+1 (full 112 w) x 128 cout.
// LDS x tile: [4 rows][114 cols][64 ci] bf16, swizzled: byte = r*14592 + col*128 + ((ci*2)^((col&7)<<4))
__global__ __launch_bounds__(256, 2) void conv_746(
    const float* __restrict__ x, const unsigned char* __restrict__ wsb,
    const float* __restrict__ bias, float* __restrict__ out) {
  __shared__ __align__(16) unsigned char lds[58368];
  const int bx = blockIdx.x;
  const int n = bx / 56, hpair = bx % 56, h0 = hpair * 2;
  const int tid = threadIdx.x;
  const int lane = tid & 63, wid = tid >> 6;
  const int wr = wid >> 1, wc2 = wid & 1;     // wave row (0/1), wave cout-half (0/1)
  const int lw = lane & 15, hq = lane >> 4;

  float bb[4];
#pragma unroll
  for (int nf = 0; nf < 4; ++nf) bb[nf] = bias[wc2 * 64 + nf * 16 + lw];

  const f32x4 z4 = {0.f, 0.f, 0.f, 0.f};
  // zero pad columns 0 (w=-1) and 113 (w=112), all 4 rows
  if (tid < 64) {
    const int r = tid >> 4, csel = (tid >> 3) & 1, s = tid & 7;
    const int col = csel ? 113 : 0;
    *(f32x4*)&lds[r * 14592 + col * 128 + s * 16] = z4;
  }
  // stage x rows h0-1..h0+2, fp32 -> bf16, swizzled LDS writes
  const int wst = tid & 127;       // w coord (112..127 idle)
  const int cig = tid >> 7;        // ci half
  const float* xn = x + (size_t)n * 802816;
#pragma unroll
  for (int r = 0; r < 4; ++r) {
    const int h = h0 - 1 + r;
    if (h < 0 || h >= 112) {       // out-of-image row -> zeros
      for (int off = tid * 16; off < 14592; off += 4096)
        *(f32x4*)&lds[r * 14592 + off] = z4;
    } else if (wst < 112) {
      const float* xr = xn + (size_t)h * 112 + wst;
      const int col = wst + 1;
      const int cbase = r * 14592 + col * 128;
      const int xorv = (col & 7) << 4;
#pragma unroll
      for (int i = 0; i < 16; ++i) {
        const int ci0 = cig * 32 + i * 2;
        const float f0 = xr[(size_t)ci0 * 12544];
        const float f1 = xr[(size_t)(ci0 + 1) * 12544];
        const unsigned pk = (unsigned)f2bf(f0) | ((unsigned)f2bf(f1) << 16);
        *(unsigned*)&lds[cbase + ((ci0 * 2) ^ xorv)] = pk;
      }
    }
  }
  __syncthreads();

  // implicit GEMM: M=112 w per wave-row, N=64 couts per wave-half, K=576
  f32x4 acc[7][4];
#pragma unroll
  for (int f = 0; f < 7; ++f)
#pragma unroll
    for (int nf = 0; nf < 4; ++nf) acc[f][nf] = z4;

#pragma unroll
  for (int kh = 0; kh < 3; ++kh) {
#pragma unroll
    for (int kw = 0; kw < 3; ++kw) {
      const int xorv = ((lw + kw) & 7) << 4;           // (col&7)<<4, col = f*16+lw+kw
      const int abase0 = (wr + kh) * 14592 + (lw + kw) * 128;
#pragma unroll
      for (int ck = 0; ck < 2; ++ck) {
        bf16x8 bfr[4];
        const unsigned char* bp =
            wsb + (((size_t)(((kh * 3 + kw) * 2 + ck) * 8 + wc2 * 4) * 64 + lane) << 4);
#pragma unroll
        for (int nf = 0; nf < 4; ++nf)
          bfr[nf] = *(const bf16x8*)(bp + (nf << 10));  // nf*64 lanes*16B
        const int abase = abase0 + ((ck * 64 + hq * 16) ^ xorv);
#pragma unroll
        for (int f = 0; f < 7; ++f) {
          const bf16x8 a = *(const bf16x8*)&lds[abase + f * 2048];
#pragma unroll
          for (int nf = 0; nf < 4; ++nf)
            acc[f][nf] = __builtin_amdgcn_mfma_f32_16x16x32_bf16(a, bfr[nf], acc[f][nf], 0, 0, 0);
        }
      }
    }
  }

  // bias + relu + horizontal pool (in-lane: regs are 4 consecutive w)
  __syncthreads();   // x tile dead; reuse LDS for pooling exchange
  float pl0[7][4], pl1[7][4];
#pragma unroll
  for (int f = 0; f < 7; ++f)
#pragma unroll
    for (int nf = 0; nf < 4; ++nf) {
      const float a0 = fmaxf(acc[f][nf][0] + bb[nf], 0.f);
      const float a1 = fmaxf(acc[f][nf][1] + bb[nf], 0.f);
      const float a2 = fmaxf(acc[f][nf][2] + bb[nf], 0.f);
      const float a3 = fmaxf(acc[f][nf][3] + bb[nf], 0.f);
      pl0[f][nf] = fmaxf(a0, a1);
      pl1[f][nf] = fmaxf(a2, a3);
    }
  // vertical pool: wave-row 0 posts partials, wave-row 1 combines
  float* pb = (float*)lds;    // [wc2][56 pw][64 couts] f32
  if (wr == 0) {
#pragma unroll
    for (int f = 0; f < 7; ++f)
#pragma unroll
      for (int nf = 0; nf < 4; ++nf) {
        const int bse = wc2 * 3584 + (f * 8 + hq * 2) * 64 + nf * 16 + lw;
        pb[bse] = pl0[f][nf];
        pb[bse + 64] = pl1[f][nf];
      }
  }
  __syncthreads();
  float* pb2 = (float*)(lds + 28672);   // [128 couts][56 pw] f32, for coalesced store
  if (wr == 1) {
#pragma unroll
    for (int f = 0; f < 7; ++f)
#pragma unroll
      for (int nf = 0; nf < 4; ++nf) {
        const int bse = wc2 * 3584 + (f * 8 + hq * 2) * 64 + nf * 16 + lw;
        const float v0 = fmaxf(pl0[f][nf], pb[bse]);
        const float v1 = fmaxf(pl1[f][nf], pb[bse + 64]);
        const int ob = (wc2 * 64 + nf * 16 + lw) * 56 + f * 8 + hq * 2;
        pb2[ob] = v0;
        pb2[ob + 1] = v1;
      }
  }
  __syncthreads();
  // cooperative coalesced output: [128 co][56 pw] -> out[n][co][hpair][:]
  const float* pb2c = (const float*)(lds + 28672);
#pragma unroll
  for (int i = 0; i < 7; ++i) {
    const int idx = i * 256 + tid;            // 0..1791 float4s
    const int co = idx / 14, q = idx - co * 14;
    const f32x4 v = *(const f32x4*)&pb2c[co * 56 + q * 4];
    *(f32x4*)(out + (size_t)(n * 128 + co) * 3136 + hpair * 56 + q * 4) = v;
  }
}

// ---- safety fallback if workspace is too small (should never trigger)
__global__ __launch_bounds__(256) void naive_746(
    const float* __restrict__ x, const float* __restrict__ wt,
    const float* __restrict__ bias, float* __restrict__ out) {
  int idx = blockIdx.x * 256 + threadIdx.x;
  if (idx >= 12845056) return;
  int pw = idx % 56; int t = idx / 56;
  int ph = t % 56; t /= 56;
  int co = t % 128; int n = t / 128;
  float best = 0.f;  // relu output >= 0
  for (int dh = 0; dh < 2; ++dh)
    for (int dw = 0; dw < 2; ++dw) {
      int oh = ph * 2 + dh, ow = pw * 2 + dw;
      float acc = bias[co];
      for (int ci = 0; ci < 64; ++ci) {
        const float* xp = x + ((size_t)(n * 64 + ci) * 112) * 112;
        const float* wp = wt + (co * 64 + ci) * 9;
        for (int kh = 0; kh < 3; ++kh) {
          int ih = oh + kh - 1; if (ih < 0 || ih >= 112) continue;
          for (int kw = 0; kw < 3; ++kw) {
            int iw = ow + kw - 1; if (iw < 0 || iw >= 112) continue;
            acc += xp[ih * 112 + iw] * wp[kh * 3 + kw];
          }
        }
      }
      best = fmaxf(best, fmaxf(acc, 0.f));
    }
  out[idx] = best;
}

extern "C" void kernel_launch(void* const* d_in, const int* in_sizes, int n_in,
                              void* d_out, int out_size, void* d_ws, size_t ws_size,
                              hipStream_t stream) {
  const float* x = (const float*)d_in[0];
  const float* w = (const float*)d_in[1];
  const float* b = (const float*)d_in[2];
  float* o = (float*)d_out;
  if (ws_size < (size_t)WF_BYTES) {
    naive_746<<<dim3((12845056 + 255) / 256), dim3(256), 0, stream>>>(x, w, b, o);
    return;
  }
  unsigned short* wf = (unsigned short*)d_ws;
  wxf_746<<<dim3(144), dim3(64), 0, stream>>>(w, wf);
  conv_746<<<dim3(1792), dim3(256), 0, stream>>>(x, (const unsigned char*)d_ws, b, o);
}

// Round 2
// 83.921 us; speedup vs baseline: 1.0675x; 1.0675x over previous
//
#include <hip/hip_runtime.h>

typedef __bf16 bf16x8 __attribute__((ext_vector_type(8)));
typedef float  f32x4  __attribute__((ext_vector_type(4)));

__device__ __forceinline__ unsigned short f2bf(float f) {
  unsigned u = __float_as_uint(f);
  u += 0x7FFFu + ((u >> 16) & 1u);   // round-to-nearest-even
  return (unsigned short)(u >> 16);
}

#define WF_BYTES 147456  // 9 taps * 2 ci-chunks * 8 cout-blocks * 64 lanes * 16 B

// ---- weight transform: W[128][64][3][3] f32 -> bf16 MFMA B-fragment layout
// wf[(((kh*3+kw)*2+ck)*8+nb)*64 + lane][j] = W[nb*16+(lane&15)][ck*32+(lane>>4)*8+j][kh][kw]
__global__ __launch_bounds__(64) void wxf_746(const float* __restrict__ w,
                                              unsigned short* __restrict__ wf) {
  const int b = blockIdx.x;            // 0..143
  const int lane = threadIdx.x;        // 0..63
  const int nb = b & 7, ck = (b >> 3) & 1, pos = b >> 4;
  const int kh = pos / 3, kw = pos % 3;
  const int co = nb * 16 + (lane & 15);
  const int ci0 = ck * 32 + ((lane >> 4) << 3);
  unsigned short* o = wf + ((size_t)(b * 64 + lane) << 3);
#pragma unroll
  for (int j = 0; j < 8; ++j)
    o[j] = f2bf(w[((co * 64 + ci0 + j) * 3 + kh) * 3 + kw]);
}

// ---- fused conv3x3 + bias + relu + maxpool2x2, implicit GEMM, bf16 MFMA
// 1 WG (512 thr, 8 waves) = (n, pooled row hpair). Conv rows h0,h0+1 x 128 cout.
// Waves: wr = wid>>2 (conv row), wc = wid&3 (32-cout quarter). 16 waves/CU.
// LDS x tile: [4 rows][114 cols][64 ci] bf16, swizzle byte = r*14592 + col*128 + ((ci*2)^((col&7)<<4))
__global__ __launch_bounds__(512, 4) void conv_746(
    const float* __restrict__ x, const unsigned char* __restrict__ wsb,
    const float* __restrict__ bias, float* __restrict__ out) {
  __shared__ __align__(16) unsigned char lds[58368];
  const int bx = blockIdx.x;
  const int n = bx / 56, hpair = bx % 56, h0 = hpair * 2;
  const int tid = threadIdx.x;
  const int lane = tid & 63, wid = tid >> 6;
  const int wr = wid >> 2, wc = wid & 3;      // wave conv-row (0/1), wave cout-quarter (0..3)
  const int lw = lane & 15, hq = lane >> 4;

  float bb[2];
#pragma unroll
  for (int nf = 0; nf < 2; ++nf) bb[nf] = bias[(wc * 2 + nf) * 16 + lw];

  const f32x4 z4 = {0.f, 0.f, 0.f, 0.f};
  // zero pad columns 0 (w=-1) and 113 (w=112), all 4 rows
  if (tid < 64) {
    const int r = tid >> 4, csel = (tid >> 3) & 1, s = tid & 7;
    const int col = csel ? 113 : 0;
    *(f32x4*)&lds[r * 14592 + col * 128 + s * 16] = z4;
  }
  // stage x rows h0-1..h0+2, fp32 -> bf16, swizzled LDS writes
  const int wst = tid & 127;       // w coord (112..127 idle)
  const int cig = tid >> 7;        // ci group of 16 (0..3)
  const float* xn = x + (size_t)n * 802816;
#pragma unroll
  for (int r = 0; r < 4; ++r) {
    const int h = h0 - 1 + r;
    if (h < 0 || h >= 112) {       // out-of-image row -> zeros
      for (int off = tid * 16; off < 14592; off += 8192)
        *(f32x4*)&lds[r * 14592 + off] = z4;
    } else if (wst < 112) {
      const float* xr = xn + (size_t)h * 112 + wst;
      const int col = wst + 1;
      const int cbase = r * 14592 + col * 128;
      const int xorv = (col & 7) << 4;
#pragma unroll
      for (int i = 0; i < 8; ++i) {
        const int ci0 = cig * 16 + i * 2;
        const float f0 = xr[(size_t)ci0 * 12544];
        const float f1 = xr[(size_t)(ci0 + 1) * 12544];
        const unsigned pk = (unsigned)f2bf(f0) | ((unsigned)f2bf(f1) << 16);
        *(unsigned*)&lds[cbase + ((ci0 * 2) ^ xorv)] = pk;
      }
    }
  }
  __syncthreads();

  // implicit GEMM: M=112 w per conv row, N=32 couts per wave, K=576
  f32x4 acc[7][2];
#pragma unroll
  for (int f = 0; f < 7; ++f)
#pragma unroll
    for (int nf = 0; nf < 2; ++nf) acc[f][nf] = z4;

#pragma unroll
  for (int kh = 0; kh < 3; ++kh) {
#pragma unroll
    for (int kw = 0; kw < 3; ++kw) {
      const int xorv = ((lw + kw) & 7) << 4;           // (col&7)<<4, col = f*16+lw+kw
      const int abase0 = (wr + kh) * 14592 + (lw + kw) * 128;
#pragma unroll
      for (int ck = 0; ck < 2; ++ck) {
        bf16x8 bfr[2];
        const unsigned char* bp =
            wsb + (((size_t)(((kh * 3 + kw) * 2 + ck) * 8 + wc * 2) * 64 + lane) << 4);
        bfr[0] = *(const bf16x8*)bp;
        bfr[1] = *(const bf16x8*)(bp + 1024);           // +1 cout block = 64 lanes*16B
        const int abase = abase0 + ((ck * 64 + hq * 16) ^ xorv);
#pragma unroll
        for (int f = 0; f < 7; ++f) {
          const bf16x8 a = *(const bf16x8*)&lds[abase + f * 2048];
          acc[f][0] = __builtin_amdgcn_mfma_f32_16x16x32_bf16(a, bfr[0], acc[f][0], 0, 0, 0);
          acc[f][1] = __builtin_amdgcn_mfma_f32_16x16x32_bf16(a, bfr[1], acc[f][1], 0, 0, 0);
        }
      }
    }
  }

  // bias + relu + horizontal pool (in-lane: acc regs are 4 consecutive w)
  __syncthreads();   // x tile dead; reuse LDS as pool buffer [128 co][56 pw] f32
  float pl0[7][2], pl1[7][2];
#pragma unroll
  for (int f = 0; f < 7; ++f)
#pragma unroll
    for (int nf = 0; nf < 2; ++nf) {
      const float a0 = fmaxf(acc[f][nf][0] + bb[nf], 0.f);
      const float a1 = fmaxf(acc[f][nf][1] + bb[nf], 0.f);
      const float a2 = fmaxf(acc[f][nf][2] + bb[nf], 0.f);
      const float a3 = fmaxf(acc[f][nf][3] + bb[nf], 0.f);
      pl0[f][nf] = fmaxf(a0, a1);
      pl1[f][nf] = fmaxf(a2, a3);
    }
  float* pb = (float*)lds;    // [128 co][56 pw]
  if (wr == 0) {
#pragma unroll
    for (int f = 0; f < 7; ++f)
#pragma unroll
      for (int nf = 0; nf < 2; ++nf) {
        const int co = (wc * 2 + nf) * 16 + lw;
        const int pw = f * 8 + hq * 2;
        pb[co * 56 + pw] = pl0[f][nf];
        pb[co * 56 + pw + 1] = pl1[f][nf];
      }
  }
  __syncthreads();
  if (wr == 1) {   // vertical pool: combine with row-0 partials, write back
#pragma unroll
    for (int f = 0; f < 7; ++f)
#pragma unroll
      for (int nf = 0; nf < 2; ++nf) {
        const int co = (wc * 2 + nf) * 16 + lw;
        const int pw = f * 8 + hq * 2;
        const float v0 = fmaxf(pl0[f][nf], pb[co * 56 + pw]);
        const float v1 = fmaxf(pl1[f][nf], pb[co * 56 + pw + 1]);
        pb[co * 56 + pw] = v0;
        pb[co * 56 + pw + 1] = v1;
      }
  }
  __syncthreads();
  // cooperative coalesced output: [128 co][56 pw] -> out[n][co][hpair][:]
  const float* pbc = (const float*)lds;
#pragma unroll
  for (int i = 0; i < 4; ++i) {
    const int idx = i * 512 + tid;            // 0..1791 float4s
    if (idx < 1792) {
      const int co = idx / 14, q = idx - co * 14;
      const f32x4 v = *(const f32x4*)&pbc[co * 56 + q * 4];
      *(f32x4*)(out + (size_t)(n * 128 + co) * 3136 + hpair * 56 + q * 4) = v;
    }
  }
}

// ---- safety fallback if workspace is too small (should never trigger)
__global__ __launch_bounds__(256) void naive_746(
    const float* __restrict__ x, const float* __restrict__ wt,
    const float* __restrict__ bias, float* __restrict__ out) {
  int idx = blockIdx.x * 256 + threadIdx.x;
  if (idx >= 12845056) return;
  int pw = idx % 56; int t = idx / 56;
  int ph = t % 56; t /= 56;
  int co = t % 128; int n = t / 128;
  float best = 0.f;  // relu output >= 0
  for (int dh = 0; dh < 2; ++dh)
    for (int dw = 0; dw < 2; ++dw) {
      int oh = ph * 2 + dh, ow = pw * 2 + dw;
      float acc = bias[co];
      for (int ci = 0; ci < 64; ++ci) {
        const float* xp = x + ((size_t)(n * 64 + ci) * 112) * 112;
        const float* wp = wt + (co * 64 + ci) * 9;
        for (int kh = 0; kh < 3; ++kh) {
          int ih = oh + kh - 1; if (ih < 0 || ih >= 112) continue;
          for (int kw = 0; kw < 3; ++kw) {
            int iw = ow + kw - 1; if (iw < 0 || iw >= 112) continue;
            acc += xp[ih * 112 + iw] * wp[kh * 3 + kw];
          }
        }
      }
      best = fmaxf(best, fmaxf(acc, 0.f));
    }
  out[idx] = best;
}

extern "C" void kernel_launch(void* const* d_in, const int* in_sizes, int n_in,
                              void* d_out, int out_size, void* d_ws, size_t ws_size,
                              hipStream_t stream) {
  const float* x = (const float*)d_in[0];
  const float* w = (const float*)d_in[1];
  const float* b = (const float*)d_in[2];
  float* o = (float*)d_out;
  if (ws_size < (size_t)WF_BYTES) {
    naive_746<<<dim3((12845056 + 255) / 256), dim3(256), 0, stream>>>(x, w, b, o);
    return;
  }
  unsigned short* wf = (unsigned short*)d_ws;
  wxf_746<<<dim3(144), dim3(64), 0, stream>>>(w, wf);
  conv_746<<<dim3(1792), dim3(512), 0, stream>>>(x, (const unsigned char*)d_ws, b, o);
}